// Round 2
// baseline (256.364 us; speedup 1.0000x reference)
//
#include <hip/hip_runtime.h>

// MHA: B=2, S=2048, D=1024, H=16, DK=64. I/O bf16 (harness-confirmed R4);
// dual fp32 path retained via runtime detect. mask int32.
//
// Pipeline (ws 16 MB; d_out doubles as V scratch):
//   0) detect: classify d_in[0] bf16 vs fp32 -> flag in ws
//   1) gemmk<128,0>: Q/K/V proj y = x @ W^T (one launch, z selects tensor).
//        z=0: Qh [B,H,S,DK], pre-scaled by 0.125*log2e (softmax fold)
//        z=1: Kh [B,H,S,DK]
//        z=2: Vt [B,H,DK,S]  (transposed, bf16x4-packed stores)
//   2) attn (R11): flash, 128 q-rows/block (32/wave, 2 q-tiles), 64
//        keys/iter, K/V LDS dbuf via global_load_lds w16 (XOR-swizzled).
//        SWAPPED score MFMA: s = mfma(Kfrag, Qfrag, bias) -> lane holds
//        score[key=quad*4+r][q=l15]; keys are lane-local so
//          - lsum is one scalar/lane/q-tile (finish: 2 shfl_xor)
//          - P store is packed ds_write_b64 (4 consecutive keys)
//          - P read back is plain ds_read_b128 = PV A-frag directly
//        16B-chunk XOR swizzle (^l15&7) both sides; at bank data-floor.
//        K/V fragments shared across both q-tiles. mask folded into the
//        score-accumulator init (per-key bias, int4 loads). ctx IN PLACE
//        over Qh. grid 512.
//   3) gemmk<64,1>: out = ctx @ Wo^T -> d_out (512 blocks).
//
// MFMA 16x16x32 bf16 layouts (verified):
//   A: lane holds A[m=lane&15][k=(lane>>4)*8+j]
//   B: lane holds B[k=(lane>>4)*8+j][n=lane&15]
//   C/D: col=lane&15, row=(lane>>4)*4+reg
//
// R4: no u16/bf16 punning (TBAA reorder -> NaN).
// R5: per-wave direct global K/V = latency bound -> LDS staging.
// R6: VGPR-roundtrip staging = latency bound -> global_load_lds w16.
// R8 REGRESSION: dual MFMA orientation in gemm K-loop (VGPR 84->108).
// R9: BK=64 gemms WIN (kept verbatim).
// R10 FAILED (absmax 0.22): ds_read_b64_tr_b16 gather model wrong (assumed
//   per-lane 32B-stride walk; HW subtile stride is fixed 16 bf16). The
//   2-q-tile restructure itself is layout-safe and KEPT.
// R11 (this round): packed P round-trip WITHOUT transpose HW, via swapped
//   score-MFMA operands (key axis -> C/D row). DS ops/iter/wave 68 -> 28
//   for 32 MFMA. All standard ops; asm memory fence between P store/read
//   phases (TBAA bf16x4-store vs bf16x8-load reorder hazard, R4 lesson).

typedef __bf16 bf16x8 __attribute__((ext_vector_type(8)));
typedef __bf16 bf16x4 __attribute__((ext_vector_type(4)));
typedef float f32x4 __attribute__((ext_vector_type(4)));

#define B_ 2
#define S_ 2048
#define D_ 1024
#define H_ 16
#define DK_ 64
#define QSCALE 0.18033688011112042f  // 0.125 * log2(e)

// ---------------------------------------------------------------------------
__global__ void detect_dtype(const unsigned int* __restrict__ qw,
                             int* __restrict__ flag) {
  int cnt = 0;
#pragma unroll
  for (int i = 0; i < 4; ++i) {
    unsigned int w = qw[threadIdx.x + 64 * i];
    int e = (w >> 7) & 0xFF;
    cnt += (e >= 100 && e <= 140) ? 1 : 0;
  }
#pragma unroll
  for (int off = 32; off > 0; off >>= 1) cnt += __shfl_down(cnt, off, 64);
  if (threadIdx.x == 0) *flag = (cnt >= 128) ? 0 : 1;
}

__device__ __forceinline__ bf16x8 load8cvt(const void* base, size_t eoff,
                                           bool f32) {
  if (!f32) return *(const bf16x8*)((const __bf16*)base + eoff);
  const float* p = (const float*)base + eoff;
  bf16x8 r;
#pragma unroll
  for (int j = 0; j < 8; ++j) r[j] = (__bf16)p[j];
  return r;
}

// async 16B global -> LDS (lds dest = wave-uniform base + lane*16)
__device__ __forceinline__ void async_cp16(const __bf16* g, __bf16* l) {
  __builtin_amdgcn_global_load_lds(
      (const __attribute__((address_space(1))) unsigned int*)g,
      (__attribute__((address_space(3))) unsigned int*)l, 16, 0, 0);
}

// ---------------------------------------------------------------------------
// GEMM (R9 verbatim): C[M,N] = X[M,K] @ W[N,K]^T, TM x 128 tile, BK=64.
// LDS unpadded [rows][64]; 16B chunks XOR-swizzled (phys j = jl ^ (row&7)).
// Staging via global_load_lds w16 (bf16) / load+convert (fp32 fallback).
// Single MFMA orientation; vt handled only in the epilogue.
// ---------------------------------------------------------------------------
template <int TM, int MODE>
__global__ __launch_bounds__(256) void gemmk(
    const void* X0, const void* X1, const void* X2,
    const void* W0, const void* W1, const void* W2,
    void* O0, void* O1, void* O2, const int* __restrict__ dflag) {
  constexpr int Kd = 1024, Nd = 1024;
  constexpr int NI = (TM == 128) ? 4 : 2;
  constexpr int ACH = TM / 32;
  constexpr int BCH = 4;
  const void* X = (blockIdx.z == 0) ? X0 : (blockIdx.z == 1 ? X1 : X2);
  const void* W = (blockIdx.z == 0) ? W0 : (blockIdx.z == 1 ? W1 : W2);
  void* O = (blockIdx.z == 0) ? O0 : (blockIdx.z == 1 ? O1 : O2);
  const bool f32io = (*dflag != 0);

  __shared__ __attribute__((aligned(16))) __bf16 As[TM * 64];
  __shared__ __attribute__((aligned(16))) __bf16 Bs[128 * 64];

  const int m0 = blockIdx.x * TM;
  const int n0 = blockIdx.y * 128;
  const int t = threadIdx.x;
  const int lane = t & 63, wave = t >> 6;
  const int l15 = lane & 15, quad = lane >> 4;
  const int wm = (TM == 128) ? (wave >> 1) * 64 : 0;
  const int wn = (TM == 128) ? (wave & 1) * 64 : wave * 32;

  const __bf16* gA[ACH];
  __bf16* ldsA[ACH];
#pragma unroll
  for (int i = 0; i < ACH; ++i) {
    int c = (wave * ACH + i) * 64 + lane;
    int row = c >> 3, j = c & 7;
    int jl = j ^ (row & 7);
    ldsA[i] = &As[(wave * ACH + i) * 512];
    if (MODE == 0) {
      gA[i] = (const __bf16*)X + (size_t)(m0 + row) * Kd + jl * 8;
    } else {
      int gm = m0 + row;
      gA[i] = (const __bf16*)X + (size_t)(gm >> 11) * (H_ * S_ * DK_) +
              (size_t)(gm & (S_ - 1)) * DK_ + jl * 8;
    }
  }
  const __bf16* gB[BCH];
  __bf16* ldsB[BCH];
#pragma unroll
  for (int i = 0; i < BCH; ++i) {
    int c = (wave * BCH + i) * 64 + lane;
    int row = c >> 3, j = c & 7;
    int jl = j ^ (row & 7);
    ldsB[i] = &Bs[(wave * BCH + i) * 512];
    gB[i] = (const __bf16*)W + (size_t)(n0 + row) * Kd + jl * 8;
  }

  f32x4 acc[4][NI] = {};

  for (int k0 = 0; k0 < Kd; k0 += 64) {
    __syncthreads();
    if (!f32io) {
      if (MODE == 0) {
#pragma unroll
        for (int i = 0; i < ACH; ++i) async_cp16(gA[i] + k0, ldsA[i]);
      } else {
        const size_t koff = (size_t)(k0 >> 6) * (S_ * DK_);
#pragma unroll
        for (int i = 0; i < ACH; ++i) async_cp16(gA[i] + koff, ldsA[i]);
      }
#pragma unroll
      for (int i = 0; i < BCH; ++i) async_cp16(gB[i] + k0, ldsB[i]);
    } else {
#pragma unroll
      for (int i = 0; i < TM / 32; ++i) {
        int c = t + 256 * i;
        int row = c >> 3, j = c & 7;
        int jl = j ^ (row & 7);
        bf16x8 xv;
        if (MODE == 0) {
          xv = load8cvt(X, (size_t)(m0 + row) * Kd + k0 + jl * 8, true);
        } else {
          int gm = m0 + row, gk = k0 + jl * 8;
          xv = *(const bf16x8*)((const __bf16*)X +
                ((((size_t)(gm >> 11) * H_ + (gk >> 6)) * S_) +
                 (gm & (S_ - 1))) * DK_ + (gk & (DK_ - 1)));
        }
        *(bf16x8*)&As[row * 64 + j * 8] = xv;
      }
#pragma unroll
      for (int i = 0; i < 4; ++i) {
        int c = t + 256 * i;
        int row = c >> 3, j = c & 7;
        int jl = j ^ (row & 7);
        bf16x8 wv = load8cvt(W, (size_t)(n0 + row) * Kd + k0 + jl * 8, true);
        *(bf16x8*)&Bs[row * 64 + j * 8] = wv;
      }
    }
    __syncthreads();

#pragma unroll
    for (int h = 0; h < 2; ++h) {
      bf16x8 af[4], bfr[NI];
#pragma unroll
      for (int mi = 0; mi < 4; ++mi) {
        int row = wm + mi * 16 + l15;
        af[mi] = *(const bf16x8*)&As[row * 64 +
                                     (((h * 4 + quad) ^ (row & 7)) << 3)];
      }
#pragma unroll
      for (int ni = 0; ni < NI; ++ni) {
        int row = wn + ni * 16 + l15;
        bfr[ni] = *(const bf16x8*)&Bs[row * 64 +
                                      (((h * 4 + quad) ^ (row & 7)) << 3)];
      }
#pragma unroll
      for (int mi = 0; mi < 4; ++mi)
#pragma unroll
        for (int ni = 0; ni < NI; ++ni)
          acc[mi][ni] = __builtin_amdgcn_mfma_f32_16x16x32_bf16(
              af[mi], bfr[ni], acc[mi][ni], 0, 0, 0);
    }
  }

  const float oscale = (MODE == 0 && blockIdx.z == 0) ? QSCALE : 1.0f;
#pragma unroll
  for (int mi = 0; mi < 4; ++mi) {
#pragma unroll
    for (int ni = 0; ni < NI; ++ni) {
      int mbase = m0 + wm + mi * 16 + quad * 4;
      int n = n0 + wn + ni * 16 + l15;
      if (MODE == 0 && blockIdx.z == 2) {
        int b = mbase >> 11, sb = mbase & (S_ - 1);
        int h = n >> 6, dk = n & (DK_ - 1);
        bf16x4 pk;
#pragma unroll
        for (int r = 0; r < 4; ++r) pk[r] = (__bf16)acc[mi][ni][r];
        *(bf16x4*)&((__bf16*)O)[((size_t)(b * H_ + h) * DK_ + dk) * S_ + sb] = pk;
      } else {
#pragma unroll
        for (int r = 0; r < 4; ++r) {
          int m = mbase + r;
          float val = acc[mi][ni][r] * oscale;
          if (MODE == 0) {
            int b = m >> 11, s = m & (S_ - 1);
            int h = n >> 6, dk = n & (DK_ - 1);
            ((__bf16*)O)[((size_t)(b * H_ + h) * S_ + s) * DK_ + dk] = (__bf16)val;
          } else {
            size_t idx = (size_t)m * Nd + n;
            if (f32io) ((float*)O)[idx] = val;
            else       ((__bf16*)O)[idx] = (__bf16)val;
          }
        }
      }
    }
  }
}

// ---------------------------------------------------------------------------
// Flash attention, R11 form: 128 q-rows/block (32/wave as 2 q-tiles), 64
// keys/iter, grid 512 (LDS 48KB -> 2 blocks/CU by grid). Swapped score
// MFMA: s = mfma(Kfrag, Qfrag, bias) -> lane holds s[key=quad*4+r][q=l15].
// P layout per wave per q-tile: [16 q][64 key] rows of 128B, 16B chunks
// XOR-swizzled by (l15&7). Store: one ds_write_b64 per (qt,tt) -- lane's
// 4 values are consecutive keys tt*16+quad*4..+3 of q-row l15, at chunk
// c = tt*2+(quad>>1), half h = quad&1. Read: one ds_read_b128 per (qt,kt)
// at chunk kt*4+quad -> PV A-frag P[q=l15][key=kt*32+quad*8+j] directly.
// Both patterns at the LDS bank data-floor (verified by hand).
// K/V fragments read once, shared by both q-tiles. Mask enters as per-key
// f32x4 bias init (int4 load per key-tile). Wave-private P: in-order LDS,
// no barriers; asm memory fence pins store phase above read phase.
// ---------------------------------------------------------------------------
__global__ __launch_bounds__(256, 2) void attn(
    const __bf16* Qh, const __bf16* __restrict__ Kh,
    const __bf16* __restrict__ Vt, const int* __restrict__ mask,
    __bf16* Out) {
  __shared__ __attribute__((aligned(16))) __bf16 Ks[2][4096];
  __shared__ __attribute__((aligned(16))) __bf16 Vs[2][4096];
  __shared__ __attribute__((aligned(16))) __bf16 P[4][2048];  // wave: 2 x [16][64]

  const int t = threadIdx.x;
  const int lane = t & 63, wave = t >> 6;
  const int l15 = lane & 15, quad = lane >> 4;
  const int qb = blockIdx.x & 15;   // 16 q-blocks of 128
  const int bh = blockIdx.x >> 4;   // b*H + h
  const int b = bh >> 4;
  const int q0 = qb * 128 + wave * 32;

  const __bf16* Q = Qh + (size_t)bh * S_ * DK_;
  const __bf16* K = Kh + (size_t)bh * S_ * DK_;
  const __bf16* V = Vt + (size_t)bh * DK_ * S_;   // [dk][s]
  const int* mk = mask + b * S_;

  bf16x8 qf[2][2];
#pragma unroll
  for (int qt = 0; qt < 2; ++qt) {
    qf[qt][0] = *(const bf16x8*)&Q[(size_t)(q0 + qt * 16 + l15) * DK_ + quad * 8];
    qf[qt][1] = *(const bf16x8*)&Q[(size_t)(q0 + qt * 16 + l15) * DK_ + 32 + quad * 8];
  }

  f32x4 o[2][4] = {};
  float lsum[2] = {0.f, 0.f};

  // loop-invariant P element offsets (within P[wave], before qt*1024)
  int pst[4], prd[2];
#pragma unroll
  for (int tt = 0; tt < 4; ++tt)
    pst[tt] = l15 * 64 + (((tt * 2 + (quad >> 1)) ^ (l15 & 7)) << 3) +
              (quad & 1) * 4;
#pragma unroll
  for (int kt = 0; kt < 2; ++kt)
    prd[kt] = l15 * 64 + (((kt * 4 + quad) ^ (l15 & 7)) << 3);

  // prologue: stage tile 0 into buf 0
#pragma unroll
  for (int i = 0; i < 2; ++i) {
    int l = wave * 128 + i * 64 + lane;
    int row = l >> 3, jg = (l & 7) ^ (row & 7);
    async_cp16(K + (size_t)row * DK_ + jg * 8, &Ks[0][(size_t)(l - lane) * 8]);
    async_cp16(V + (size_t)row * S_ + jg * 8, &Vs[0][(size_t)(l - lane) * 8]);
  }
  __syncthreads();

  for (int kb = 0; kb < S_; kb += 64) {
    const int cur = (kb >> 6) & 1;
    if (kb + 64 < S_) {
#pragma unroll
      for (int i = 0; i < 2; ++i) {
        int l = wave * 128 + i * 64 + lane;
        int row = l >> 3, jg = (l & 7) ^ (row & 7);
        async_cp16(K + (size_t)(kb + 64 + row) * DK_ + jg * 8,
                   &Ks[cur ^ 1][(size_t)(l - lane) * 8]);
        async_cp16(V + (size_t)row * S_ + (kb + 64) + jg * 8,
                   &Vs[cur ^ 1][(size_t)(l - lane) * 8]);
      }
    }

    // ---- scores (SWAPPED): s[key=quad*4+r][q=l15]; K frags shared ----
    const __bf16* ks = &Ks[cur][0];
    f32x4 s[2][4];
#pragma unroll
    for (int tt = 0; tt < 4; ++tt) {
      int row = tt * 16 + l15;
      bf16x8 kf0 = *(const bf16x8*)&ks[row * 64 + ((quad ^ (l15 & 7)) << 3)];
      bf16x8 kf1 = *(const bf16x8*)&ks[row * 64 + (((4 + quad) ^ (l15 & 7)) << 3)];
      // per-key mask bias: keys tt*16 + quad*4 .. +3
      int4 m4 = *(const int4*)&mk[kb + tt * 16 + quad * 4];
      f32x4 z;
      z[0] = m4.x ? 0.f : -1e9f;
      z[1] = m4.y ? 0.f : -1e9f;
      z[2] = m4.z ? 0.f : -1e9f;
      z[3] = m4.w ? 0.f : -1e9f;
      f32x4 z0 = __builtin_amdgcn_mfma_f32_16x16x32_bf16(kf0, qf[0][0], z, 0, 0, 0);
      s[0][tt] = __builtin_amdgcn_mfma_f32_16x16x32_bf16(kf1, qf[0][1], z0, 0, 0, 0);
      f32x4 z1 = __builtin_amdgcn_mfma_f32_16x16x32_bf16(kf0, qf[1][0], z, 0, 0, 0);
      s[1][tt] = __builtin_amdgcn_mfma_f32_16x16x32_bf16(kf1, qf[1][1], z1, 0, 0, 0);
    }

    // ---- V fragments (issue while exp phase runs; shared by q-tiles) ----
    const __bf16* vs = &Vs[cur][0];
    bf16x8 vf[2][4];
#pragma unroll
    for (int kt = 0; kt < 2; ++kt)
#pragma unroll
      for (int nt = 0; nt < 4; ++nt) {
        int dk = nt * 16 + l15;
        vf[kt][nt] =
            *(const bf16x8*)&vs[dk * 64 + (((kt * 4 + quad) ^ (l15 & 7)) << 3)];
      }

    // ---- exp2 + packed P store: one b64 per (qt,tt) ----
#pragma unroll
    for (int qt = 0; qt < 2; ++qt) {
      float acc = 0.f;
#pragma unroll
      for (int tt = 0; tt < 4; ++tt) {
        bf16x4 pk;
#pragma unroll
        for (int r = 0; r < 4; ++r) {
          float e = __builtin_exp2f(s[qt][tt][r]);   // Q carries 0.125*log2e
          acc += e;
          pk[r] = (__bf16)e;
        }
        *(bf16x4*)&P[wave][qt * 1024 + pst[tt]] = pk;
      }
      lsum[qt] += acc;
    }

    asm volatile("" ::: "memory");  // pin P stores above the P reads (TBAA)

    // ---- PV: P read back as A-frag via b128; V frags shared ----
#pragma unroll
    for (int qt = 0; qt < 2; ++qt)
#pragma unroll
      for (int kt = 0; kt < 2; ++kt) {
        bf16x8 pf = *(const bf16x8*)&P[wave][qt * 1024 + prd[kt]];
#pragma unroll
        for (int nt = 0; nt < 4; ++nt)
          o[qt][nt] = __builtin_amdgcn_mfma_f32_16x16x32_bf16(
              pf, vf[kt][nt], o[qt][nt], 0, 0, 0);
      }

    __syncthreads();  // drains staging vmcnt; separates buffer reuse
  }

  // lsum finish: all keys of a q-row live in lanes with same l15
#pragma unroll
  for (int qt = 0; qt < 2; ++qt) {
    float v = lsum[qt];
    v += __shfl_xor(v, 16, 64);
    v += __shfl_xor(v, 32, 64);
    lsum[qt] = v;  // every lane: sum for q = l15 (of tile qt)
  }

#pragma unroll
  for (int qt = 0; qt < 2; ++qt) {
    float rinv[4];
#pragma unroll
    for (int r = 0; r < 4; ++r)
      rinv[r] = 1.0f / __shfl(lsum[qt], quad * 4 + r, 64);
#pragma unroll
    for (int nt = 0; nt < 4; ++nt)
#pragma unroll
      for (int r = 0; r < 4; ++r) {
        int qrow = q0 + qt * 16 + quad * 4 + r;
        Out[(size_t)bh * S_ * DK_ + (size_t)qrow * DK_ + nt * 16 + l15] =
            (__bf16)(o[qt][nt][r] * rinv[r]);
      }
  }
}

extern "C" void kernel_launch(void* const* d_in, const int* in_sizes, int n_in,
                              void* d_out, int out_size, void* d_ws, size_t ws_size,
                              hipStream_t stream) {
  const void* q = d_in[0];
  const void* k = d_in[1];
  const void* v = d_in[2];
  const int* mask = (const int*)d_in[3];
  const void* Wq = d_in[4];
  const void* Wk = d_in[5];
  const void* Wv = d_in[6];
  const void* Wo = d_in[7];

  const size_t NE = (size_t)B_ * H_ * S_ * DK_;  // 4,194,304 elems
  __bf16* Qh = (__bf16*)d_ws;                    // ws[0 : 8M)  -> becomes ctx
  __bf16* Kh = Qh + NE;                          // ws[8M : 16M)
  int* dflag = (int*)((char*)d_ws + 2 * NE * sizeof(__bf16));
  __bf16* Vt = (__bf16*)d_out;                   // scratch; dead before final write

  detect_dtype<<<1, 64, 0, stream>>>((const unsigned int*)q, dflag);
  dim3 g1(32, 8, 3);
  gemmk<128, 0><<<g1, 256, 0, stream>>>(q, k, v, Wq, Wk, Wv, Qh, Kh, Vt, dflag);
  attn<<<512, 256, 0, stream>>>(Qh, Kh, Vt, mask, Qh);
  dim3 g2(64, 8, 1);
  gemmk<64, 1><<<g2, 256, 0, stream>>>(Qh, Qh, Qh, Wo, Wo, Wo, d_out, d_out,
                                       d_out, dflag);
}